// Round 1
// baseline (455.038 us; speedup 1.0000x reference)
//
#include <hip/hip_runtime.h>

// ---------------- problem constants ----------------
#define B_    2
#define Q_    2048
#define HID_  2048
#define HQ_   16
#define HKV_  4
#define D_    128
#define NQKV  3072          // HQ*D + 2*HKV*D
#define QS_   2048          // q block size in qkv row
#define KVS_  512           // k block size in qkv row
#define SCALE_ 0.08838834764831843f   // D^-0.5
#define LOG2_THETA 19.931568569324174f // log2(1e6)

typedef unsigned short u16;
typedef __attribute__((ext_vector_type(8))) short bf16x8;
typedef __attribute__((ext_vector_type(4))) float f32x4;

__device__ __forceinline__ u16 f2bf(float x) {
  union { float f; unsigned int u; } v; v.f = x;
  unsigned int r = v.u + 0x7FFFu + ((v.u >> 16) & 1u);
  return (u16)(r >> 16);
}

// async global->LDS, 16B per lane; lds must be the wave-uniform base
__device__ __forceinline__ void gl2lds16(u16* lds, const u16* g) {
  __builtin_amdgcn_global_load_lds((const __attribute__((address_space(1))) void*)g,
                                   (__attribute__((address_space(3))) void*)lds,
                                   16, 0, 0);
}

// ---------------- fp32 -> bf16 cast ----------------
__global__ __launch_bounds__(256) void cvt_bf16(const float* __restrict__ in,
                                                u16* __restrict__ out, int n4) {
  int i = blockIdx.x * 256 + threadIdx.x;
  if (i < n4) {
    float4 v = *(const float4*)(in + (size_t)i * 4);
    ushort4 o;
    o.x = f2bf(v.x); o.y = f2bf(v.y); o.z = f2bf(v.z); o.w = f2bf(v.w);
    *(ushort4*)(out + (size_t)i * 4) = o;
  }
}

// ---------------- bf16 GEMM, C = A * B^T (A: MxK, B: NxK, C: MxN fp32) ------
// m97 structure: 128x128 tile, BK=32, 4 waves (2x2), 4x4 MFMA tiles per wave.
__global__ __launch_bounds__(256) void gemm_bt(const u16* __restrict__ A,
                                               const u16* __restrict__ Bw,
                                               float* __restrict__ C,
                                               int M, int N, int K) {
  __shared__ __align__(16) u16 As[128 * 32];
  __shared__ __align__(16) u16 Bs[128 * 32];
  const int tid = threadIdx.x;
  const int wave = tid >> 6, lane = tid & 63;
  const int wm = wave & 1, wn = wave >> 1;
  const int row16 = lane & 15, quad = lane >> 4;
  const int lr = lane >> 2, lp = lane & 3;
  const int m0 = blockIdx.x * 128, n0 = blockIdx.y * 128;
  f32x4 acc[4][4] = {};
  for (int k0 = 0; k0 < K; k0 += 32) {
    __syncthreads();
#pragma unroll
    for (int i = 0; i < 2; i++) {
      int r = wave * 16 + i * 64 + lr;          // tile row this lane fetches
      gl2lds16(As + (size_t)(wave * 64 + i * 256) * 8,
               A + (size_t)(m0 + r) * K + k0 + lp * 8);
      gl2lds16(Bs + (size_t)(wave * 64 + i * 256) * 8,
               Bw + (size_t)(n0 + r) * K + k0 + lp * 8);
    }
    __syncthreads();
    bf16x8 af[4], bfr[4];
#pragma unroll
    for (int t = 0; t < 4; t++) {
      af[t]  = *(const bf16x8*)(As + (wm * 64 + t * 16 + row16) * 32 + quad * 8);
      bfr[t] = *(const bf16x8*)(Bs + (wn * 64 + t * 16 + row16) * 32 + quad * 8);
    }
#pragma unroll
    for (int mi = 0; mi < 4; mi++)
#pragma unroll
      for (int ni = 0; ni < 4; ni++)
        acc[mi][ni] = __builtin_amdgcn_mfma_f32_16x16x32_bf16(af[mi], bfr[ni],
                                                              acc[mi][ni], 0, 0, 0);
  }
#pragma unroll
  for (int mi = 0; mi < 4; mi++) {
    int row = m0 + wm * 64 + mi * 16 + quad * 4;
#pragma unroll
    for (int ni = 0; ni < 4; ni++) {
      int col = n0 + wn * 64 + ni * 16 + row16;
#pragma unroll
      for (int r = 0; r < 4; r++)
        C[(size_t)(row + r) * N + col] = acc[mi][ni][r];
    }
  }
}

// ---------------- RMSNorm + RoPE for q,k; write bf16 (B,H,S,D) --------------
// one block per (b,q) row; wave handles 5 heads; lane l holds d=l and d=l+64
__global__ __launch_bounds__(256) void qk_prep(const float* __restrict__ qkv,
                                               const int* __restrict__ pos,
                                               const float* __restrict__ qw,
                                               const float* __restrict__ kw,
                                               u16* __restrict__ qb,
                                               u16* __restrict__ kb) {
  const int row = blockIdx.x;
  const int b = row >> 11, q = row & (Q_ - 1);
  const int wave = threadIdx.x >> 6, lane = threadIdx.x & 63;
  const float p = (float)pos[row];
  const float inv = exp2f(-(float)lane * (LOG2_THETA / 64.f));
  float sn, cs;
  sincosf(p * inv, &sn, &cs);
#pragma unroll
  for (int j = 0; j < 5; j++) {
    const int hh = wave * 5 + j;           // 0..19: 16 q heads then 4 k heads
    const bool isq = hh < 16;
    const int col = isq ? hh * D_ : QS_ + (hh - 16) * D_;
    const float* src = qkv + (size_t)row * NQKV + col;
    float x1 = src[lane], x2 = src[lane + 64];
    float ss = x1 * x1 + x2 * x2;
#pragma unroll
    for (int m = 1; m < 64; m <<= 1) ss += __shfl_xor(ss, m);
    const float rn = rsqrtf(ss * (1.f / 128.f) + 1e-6f);
    const float* w = isq ? qw : kw;
    float xn1 = x1 * rn * w[lane], xn2 = x2 * rn * w[lane + 64];
    float y1 = xn1 * cs - xn2 * sn;
    float y2 = xn2 * cs + xn1 * sn;
    if (isq) { y1 *= SCALE_; y2 *= SCALE_; }   // fold softmax scale into q
    u16* dst = isq ? (qb + (((size_t)b * HQ_ + hh) * Q_ + q) * D_)
                   : (kb + (((size_t)b * HKV_ + (hh - 16)) * Q_ + q) * D_);
    dst[lane]      = f2bf(y1);
    dst[lane + 64] = f2bf(y2);
  }
}

// ---------------- V transpose: qkv v-block -> vt (B,HKV,D,S) bf16 -----------
__global__ __launch_bounds__(256) void v_trans(const float* __restrict__ qkv,
                                               u16* __restrict__ vt) {
  __shared__ u16 sv[64][132];
  const int q0 = blockIdx.x * 64, hk = blockIdx.y, b = blockIdx.z;
  const int tid = threadIdx.x;
#pragma unroll
  for (int i = 0; i < 8; i++) {
    int c = tid + i * 256;                 // float4 chunk, 0..2047
    int r = c >> 5, co = (c & 31) * 4;
    float4 v = *(const float4*)(qkv + (size_t)(b * Q_ + q0 + r) * NQKV +
                                QS_ + KVS_ + hk * D_ + co);
    sv[r][co + 0] = f2bf(v.x); sv[r][co + 1] = f2bf(v.y);
    sv[r][co + 2] = f2bf(v.z); sv[r][co + 3] = f2bf(v.w);
  }
  __syncthreads();
#pragma unroll
  for (int i = 0; i < 16; i++) {
    int c = tid + i * 256;                 // ushort2 chunk, 0..4095
    int d = c >> 5, qq = (c & 31) * 2;
    ushort2 o; o.x = sv[qq][d]; o.y = sv[qq + 1][d];
    *(ushort2*)(vt + ((size_t)(b * HKV_ + hk) * D_ + d) * Q_ + q0 + qq) = o;
  }
}

// ---------------- flash attention, causal, GQA ------------------------------
// block = (q-tile of 64, head h, batch b); 4 waves x 16 q-rows each.
// LDS tiles stored [kk][row][32] (64B row stride, m97 bank profile).
__global__ __launch_bounds__(256) void attn_fwd(const u16* __restrict__ qb,
                                                const u16* __restrict__ kb,
                                                const u16* __restrict__ vt,
                                                u16* __restrict__ ob) {
  __shared__ __align__(16) u16 Ks[4][64 * 32];    // [d-chunk][key][32]
  __shared__ __align__(16) u16 Vs[2][128 * 32];   // [key-chunk][d][32]
  __shared__ __align__(16) u16 Ps[4][1024];       // per-wave [kk][row][32]
  const int q0 = blockIdx.x * 64;
  const int h = blockIdx.y, b = blockIdx.z;
  const int hk = h >> 2;                           // GQA: 4 q-heads per kv-head
  const int tid = threadIdx.x, wave = tid >> 6, lane = tid & 63;
  const int row16 = lane & 15, quad = lane >> 4;
  const int lr = lane >> 2, lp = lane & 3;
  const u16* qg = qb + (((size_t)b * HQ_ + h) * Q_ + q0) * D_;
  const u16* kg = kb + ((size_t)b * HKV_ + hk) * (size_t)Q_ * D_;
  const u16* vg = vt + ((size_t)b * HKV_ + hk) * (size_t)D_ * Q_;
  // Q fragments straight from global (one-time)
  bf16x8 qf[4];
#pragma unroll
  for (int kk = 0; kk < 4; kk++)
    qf[kk] = *(const bf16x8*)(qg + (size_t)(wave * 16 + row16) * D_ + kk * 32 + quad * 8);
  f32x4 Oa[8] = {};
  float m_run[4], l_run[4];
#pragma unroll
  for (int r = 0; r < 4; r++) { m_run[r] = -1e30f; l_run[r] = 0.f; }
  u16* pw = Ps[wave];
  const int ktiles = blockIdx.x + 1;               // causal limit
  for (int kt = 0; kt < ktiles; kt++) {
    __syncthreads();
#pragma unroll
    for (int i = 0; i < 4; i++) {
      // K tile: chunk kk=i, key=wave*16+lr, part=lp
      gl2lds16(&Ks[0][0] + (size_t)(i * 256 + wave * 64) * 8,
               kg + (size_t)kt * 64 * D_ + (size_t)(wave * 16 + lr) * D_ + i * 32 + lp * 8);
      // V tile: key-chunk i>>1, d = (i&1)*64 + wave*16 + lr
      int d = (i & 1) * 64 + wave * 16 + lr;
      gl2lds16(&Vs[0][0] + (size_t)(i * 256 + wave * 64) * 8,
               vg + (size_t)d * Q_ + kt * 64 + (i >> 1) * 32 + lp * 8);
    }
    __syncthreads();
    // S = Q K^T  (16 q-rows x 64 keys per wave)
    f32x4 S[4];
#pragma unroll
    for (int n = 0; n < 4; n++) {
      f32x4 a = {};
#pragma unroll
      for (int kk = 0; kk < 4; kk++) {
        bf16x8 kf = *(const bf16x8*)(&Ks[kk][(n * 16 + row16) * 32 + quad * 8]);
        a = __builtin_amdgcn_mfma_f32_16x16x32_bf16(qf[kk], kf, a, 0, 0, 0);
      }
      S[n] = a;
    }
    const int qrow = q0 + wave * 16 + quad * 4;
    float mt[4] = {-1e30f, -1e30f, -1e30f, -1e30f};
#pragma unroll
    for (int n = 0; n < 4; n++) {
      int key = kt * 64 + n * 16 + row16;
#pragma unroll
      for (int r = 0; r < 4; r++) {
        float s = (key <= qrow + r) ? S[n][r] : -1e30f;
        S[n][r] = s;
        mt[r] = fmaxf(mt[r], s);
      }
    }
#pragma unroll
    for (int r = 0; r < 4; r++) {
#pragma unroll
      for (int msk = 1; msk < 16; msk <<= 1)
        mt[r] = fmaxf(mt[r], __shfl_xor(mt[r], msk));
      float mn = fmaxf(m_run[r], mt[r]);
      float al = __expf(m_run[r] - mn);
      m_run[r] = mn;
      float sum = 0.f;
#pragma unroll
      for (int n = 0; n < 4; n++) {
        float pp = __expf(S[n][r] - mn);
        S[n][r] = pp;
        sum += pp;
      }
#pragma unroll
      for (int msk = 1; msk < 16; msk <<= 1)
        sum += __shfl_xor(sum, msk);
      l_run[r] = l_run[r] * al + sum;
#pragma unroll
      for (int nd = 0; nd < 8; nd++) Oa[nd][r] *= al;
    }
    // P: C-layout -> A-layout via per-wave LDS round trip
#pragma unroll
    for (int n = 0; n < 4; n++)
#pragma unroll
      for (int r = 0; r < 4; r++)
        pw[(n >> 1) * 512 + (quad * 4 + r) * 32 + (n & 1) * 16 + row16] = f2bf(S[n][r]);
#pragma unroll
    for (int kk = 0; kk < 2; kk++) {
      bf16x8 pf = *(const bf16x8*)(pw + kk * 512 + row16 * 32 + quad * 8);
#pragma unroll
      for (int nd = 0; nd < 8; nd++) {
        bf16x8 vf = *(const bf16x8*)(&Vs[kk][(nd * 16 + row16) * 32 + quad * 8]);
        Oa[nd] = __builtin_amdgcn_mfma_f32_16x16x32_bf16(pf, vf, Oa[nd], 0, 0, 0);
      }
    }
  }
  const int qrow = q0 + wave * 16 + quad * 4;
#pragma unroll
  for (int r = 0; r < 4; r++) {
    float invl = 1.f / l_run[r];
    size_t base = ((size_t)(b * Q_ + qrow + r) * HQ_ + h) * D_;
#pragma unroll
    for (int nd = 0; nd < 8; nd++)
      ob[base + nd * 16 + row16] = f2bf(Oa[nd][r] * invl);
  }
}

// ---------------- launcher ----------------
extern "C" void kernel_launch(void* const* d_in, const int* in_sizes, int n_in,
                              void* d_out, int out_size, void* d_ws, size_t ws_size,
                              hipStream_t stream) {
  const int*   positions = (const int*)  d_in[0];
  const float* hidden    = (const float*)d_in[1];
  const float* wqkv      = (const float*)d_in[4];
  const float* wo        = (const float*)d_in[5];
  const float* qnw       = (const float*)d_in[6];
  const float* knw       = (const float*)d_in[7];
  char* ws = (char*)d_ws;
  // workspace layout (113,246,208 bytes total)
  u16*  hid_bf  = (u16*)(ws);                      // 16,777,216
  u16*  wqkv_bf = (u16*)(ws + 16777216);           // 12,582,912
  u16*  wo_bf   = (u16*)(ws + 29360128);           //  8,388,608
  float* qkv    = (float*)(ws + 37748736);         // 50,331,648
  u16*  q_bf    = (u16*)(ws + 88080384);           // 16,777,216
  u16*  k_bf    = (u16*)(ws + 104857600);          //  4,194,304
  u16*  vt_bf   = (u16*)(ws + 109051904);          //  4,194,304
  u16*  attn_bf = hid_bf;                          // alias: hid_bf dead after GEMM1

  cvt_bf16<<<8192, 256, 0, stream>>>(hidden, hid_bf, 2097152);
  cvt_bf16<<<6144, 256, 0, stream>>>(wqkv, wqkv_bf, 1572864);
  cvt_bf16<<<4096, 256, 0, stream>>>(wo, wo_bf, 1048576);
  gemm_bt<<<dim3(32, 24), 256, 0, stream>>>(hid_bf, wqkv_bf, qkv, 4096, 3072, 2048);
  qk_prep<<<4096, 256, 0, stream>>>(qkv, positions, qnw, knw, q_bf, k_bf);
  v_trans<<<dim3(32, 4, 2), 256, 0, stream>>>(qkv, vt_bf);
  attn_fwd<<<dim3(32, 16, 2), 256, 0, stream>>>(q_bf, k_bf, vt_bf, attn_bf);
  gemm_bt<<<dim3(32, 16), 256, 0, stream>>>(attn_bf, wo_bf, (float*)d_out, 4096, 2048, 2048);
}

// Round 2
// 374.706 us; speedup vs baseline: 1.2144x; 1.2144x over previous
//
#include <hip/hip_runtime.h>

// ---------------- problem constants ----------------
#define B_    2
#define Q_    2048
#define HID_  2048
#define HQ_   16
#define HKV_  4
#define D_    128
#define NQKV  3072          // HQ*D + 2*HKV*D
#define QS_   2048          // q block size in qkv row
#define KVS_  512           // k block size in qkv row
// softmax scale folded into q, in exp2 domain: D^-0.5 * log2(e)
#define QSC_  (0.08838834764831843f * 1.4426950408889634f)
#define LOG2_THETA 19.931568569324174f // log2(1e6)

typedef unsigned short u16;
typedef __attribute__((ext_vector_type(8))) short bf16x8;
typedef __attribute__((ext_vector_type(4))) float f32x4;

__device__ __forceinline__ u16 f2bf(float x) {
  union { float f; unsigned int u; } v; v.f = x;
  unsigned int r = v.u + 0x7FFFu + ((v.u >> 16) & 1u);
  return (u16)(r >> 16);
}

// async global->LDS, 16B per lane; lds must be the wave-uniform base
__device__ __forceinline__ void gl2lds16(u16* lds, const u16* g) {
  __builtin_amdgcn_global_load_lds((const __attribute__((address_space(1))) void*)g,
                                   (__attribute__((address_space(3))) void*)lds,
                                   16, 0, 0);
}

// ---------------- fp32 -> bf16 cast ----------------
__global__ __launch_bounds__(256) void cvt_bf16(const float* __restrict__ in,
                                                u16* __restrict__ out, int n4) {
  int i = blockIdx.x * 256 + threadIdx.x;
  if (i < n4) {
    float4 v = *(const float4*)(in + (size_t)i * 4);
    ushort4 o;
    o.x = f2bf(v.x); o.y = f2bf(v.y); o.z = f2bf(v.z); o.w = f2bf(v.w);
    *(ushort4*)(out + (size_t)i * 4) = o;
  }
}

// ---------------- bf16 GEMM, C = A * B^T (A: MxK, B: NxK, C: MxN fp32) ------
__global__ __launch_bounds__(256) void gemm_bt(const u16* __restrict__ A,
                                               const u16* __restrict__ Bw,
                                               float* __restrict__ C,
                                               int M, int N, int K) {
  __shared__ __align__(16) u16 As[128 * 32];
  __shared__ __align__(16) u16 Bs[128 * 32];
  const int tid = threadIdx.x;
  const int wave = tid >> 6, lane = tid & 63;
  const int wm = wave & 1, wn = wave >> 1;
  const int row16 = lane & 15, quad = lane >> 4;
  const int lr = lane >> 2, lp = lane & 3;
  const int m0 = blockIdx.x * 128, n0 = blockIdx.y * 128;
  f32x4 acc[4][4] = {};
  for (int k0 = 0; k0 < K; k0 += 32) {
    __syncthreads();
#pragma unroll
    for (int i = 0; i < 2; i++) {
      int r = wave * 16 + i * 64 + lr;
      gl2lds16(As + (size_t)(wave * 64 + i * 256) * 8,
               A + (size_t)(m0 + r) * K + k0 + lp * 8);
      gl2lds16(Bs + (size_t)(wave * 64 + i * 256) * 8,
               Bw + (size_t)(n0 + r) * K + k0 + lp * 8);
    }
    __syncthreads();
    bf16x8 af[4], bfr[4];
#pragma unroll
    for (int t = 0; t < 4; t++) {
      af[t]  = *(const bf16x8*)(As + (wm * 64 + t * 16 + row16) * 32 + quad * 8);
      bfr[t] = *(const bf16x8*)(Bs + (wn * 64 + t * 16 + row16) * 32 + quad * 8);
    }
#pragma unroll
    for (int mi = 0; mi < 4; mi++)
#pragma unroll
      for (int ni = 0; ni < 4; ni++)
        acc[mi][ni] = __builtin_amdgcn_mfma_f32_16x16x32_bf16(af[mi], bfr[ni],
                                                              acc[mi][ni], 0, 0, 0);
  }
#pragma unroll
  for (int mi = 0; mi < 4; mi++) {
    int row = m0 + wm * 64 + mi * 16 + quad * 4;
#pragma unroll
    for (int ni = 0; ni < 4; ni++) {
      int col = n0 + wn * 64 + ni * 16 + row16;
#pragma unroll
      for (int r = 0; r < 4; r++)
        C[(size_t)(row + r) * N + col] = acc[mi][ni][r];
    }
  }
}

// ---------------- RMSNorm + RoPE for q,k; write bf16 (B,H,S,D) --------------
// q additionally scaled by D^-0.5 * log2(e) (attention uses exp2 softmax)
__global__ __launch_bounds__(256) void qk_prep(const float* __restrict__ qkv,
                                               const int* __restrict__ pos,
                                               const float* __restrict__ qw,
                                               const float* __restrict__ kw,
                                               u16* __restrict__ qb,
                                               u16* __restrict__ kb) {
  const int row = blockIdx.x;
  const int b = row >> 11, q = row & (Q_ - 1);
  const int wave = threadIdx.x >> 6, lane = threadIdx.x & 63;
  const float p = (float)pos[row];
  const float inv = exp2f(-(float)lane * (LOG2_THETA / 64.f));
  float sn, cs;
  sincosf(p * inv, &sn, &cs);
#pragma unroll
  for (int j = 0; j < 5; j++) {
    const int hh = wave * 5 + j;           // 0..19: 16 q heads then 4 k heads
    const bool isq = hh < 16;
    const int col = isq ? hh * D_ : QS_ + (hh - 16) * D_;
    const float* src = qkv + (size_t)row * NQKV + col;
    float x1 = src[lane], x2 = src[lane + 64];
    float ss = x1 * x1 + x2 * x2;
#pragma unroll
    for (int m = 1; m < 64; m <<= 1) ss += __shfl_xor(ss, m);
    const float rn = rsqrtf(ss * (1.f / 128.f) + 1e-6f);
    const float* w = isq ? qw : kw;
    float xn1 = x1 * rn * w[lane], xn2 = x2 * rn * w[lane + 64];
    float y1 = xn1 * cs - xn2 * sn;
    float y2 = xn2 * cs + xn1 * sn;
    if (isq) { y1 *= QSC_; y2 *= QSC_; }
    u16* dst = isq ? (qb + (((size_t)b * HQ_ + hh) * Q_ + q) * D_)
                   : (kb + (((size_t)b * HKV_ + (hh - 16)) * Q_ + q) * D_);
    dst[lane]      = f2bf(y1);
    dst[lane + 64] = f2bf(y2);
  }
}

// ---------------- V transpose: qkv v-block -> vt (B,HKV,D,S) bf16 -----------
__global__ __launch_bounds__(256) void v_trans(const float* __restrict__ qkv,
                                               u16* __restrict__ vt) {
  __shared__ u16 sv[64][132];
  const int q0 = blockIdx.x * 64, hk = blockIdx.y, b = blockIdx.z;
  const int tid = threadIdx.x;
#pragma unroll
  for (int i = 0; i < 8; i++) {
    int c = tid + i * 256;
    int r = c >> 5, co = (c & 31) * 4;
    float4 v = *(const float4*)(qkv + (size_t)(b * Q_ + q0 + r) * NQKV +
                                QS_ + KVS_ + hk * D_ + co);
    sv[r][co + 0] = f2bf(v.x); sv[r][co + 1] = f2bf(v.y);
    sv[r][co + 2] = f2bf(v.z); sv[r][co + 3] = f2bf(v.w);
  }
  __syncthreads();
#pragma unroll
  for (int i = 0; i < 16; i++) {
    int c = tid + i * 256;
    int d = c >> 5, qq = (c & 31) * 2;
    ushort2 o; o.x = sv[qq][d]; o.y = sv[qq + 1][d];
    *(ushort2*)(vt + ((size_t)(b * HKV_ + hk) * D_ + d) * Q_ + q0 + qq) = o;
  }
}

// ---------------- flash attention, causal, GQA (S^T orientation) ------------
// block = pair of 64-row q-tiles (t, 31-t) -> uniform 33 k-tile iterations.
// 4 waves x 16 q-rows. S^T = K*Q^T: C-layout col (lane&15) = q-row, so
// softmax reductions are 2 shuffles; O^T = V^T*P accumulated, transposed
// back once per strip via per-wave LDS bounce.
__global__ __launch_bounds__(256) void attn_fwd(const u16* __restrict__ qb,
                                                const u16* __restrict__ kb,
                                                const u16* __restrict__ vt,
                                                u16* __restrict__ ob) {
  __shared__ __align__(16) u16 lds[8192 + 8192 + 4608];
  u16* Ks = lds;            // [kk 0..3][key 0..63][32]   (d = kk*32 + part)
  u16* Vs = lds + 8192;     // [kk2 0..1][d 0..127][32]   (s = kt*64 + kk2*32 + part)
  u16* Ps = lds + 16384;    // per-wave [c 0..15][key 0..63], row stride 72
  const int p = blockIdx.x, h = blockIdx.y, b = blockIdx.z;
  const int hk = h >> 2;
  const int tid = threadIdx.x, wave = tid >> 6, lane = tid & 63;
  const int c = lane & 15, quad = lane >> 4;
  const int lr = lane >> 2, lp = lane & 3;
  const u16* qg = qb + ((size_t)b * HQ_ + h) * (size_t)Q_ * D_;
  const u16* kg = kb + ((size_t)b * HKV_ + hk) * (size_t)Q_ * D_;
  const u16* vg = vt + ((size_t)b * HKV_ + hk) * (size_t)D_ * Q_;
  u16* Pw = Ps + wave * 1152;        // 16 rows x 72
  u16* Bw = Ks + wave * 2176;        // bounce: 16 rows x 136 (aliases Ks/Vs)

#pragma unroll 1
  for (int tp = 0; tp < 2; tp++) {
    const int t = tp ? (31 - p) : p;
    const int q0 = t * 64;
    const int qrow = q0 + wave * 16 + c;
    bf16x8 qf[4];
#pragma unroll
    for (int kk = 0; kk < 4; kk++)
      qf[kk] = *(const bf16x8*)(qg + (size_t)qrow * D_ + kk * 32 + quad * 8);
    f32x4 Oa[8] = {};
    float m_run = -1e30f, l_run = 0.f;

#pragma unroll 1
    for (int kt = 0; kt <= t; kt++) {
      __syncthreads();
#pragma unroll
      for (int i = 0; i < 4; i++) {
        gl2lds16(Ks + (size_t)(i * 256 + wave * 64) * 8,
                 kg + ((size_t)kt * 64 + wave * 16 + lr) * D_ + i * 32 + lp * 8);
        int d = (i & 1) * 64 + wave * 16 + lr;
        gl2lds16(Vs + (size_t)(i * 256 + wave * 64) * 8,
                 vg + (size_t)d * Q_ + kt * 64 + (i >> 1) * 32 + lp * 8);
      }
      __syncthreads();
      // S^T = K * Q^T : rows = keys, cols = q-rows
      f32x4 S[4];
#pragma unroll
      for (int n = 0; n < 4; n++) {
        f32x4 a = {};
#pragma unroll
        for (int kk = 0; kk < 4; kk++) {
          bf16x8 kf = *(const bf16x8*)(Ks + kk * 2048 + (n * 16 + c) * 32 + quad * 8);
          a = __builtin_amdgcn_mfma_f32_16x16x32_bf16(kf, qf[kk], a, 0, 0, 0);
        }
        S[n] = a;
      }
      if (kt == t) {   // diagonal tile: causal mask (key <= qrow)
#pragma unroll
        for (int n = 0; n < 4; n++)
#pragma unroll
          for (int r = 0; r < 4; r++) {
            int key = kt * 64 + n * 16 + quad * 4 + r;
            if (key > qrow) S[n][r] = -1e30f;
          }
      }
      // online softmax: lane owns one q-row's 16 scores (x4 quad replicas)
      float mx = -1e30f;
#pragma unroll
      for (int n = 0; n < 4; n++)
#pragma unroll
        for (int r = 0; r < 4; r++) mx = fmaxf(mx, S[n][r]);
      mx = fmaxf(mx, __shfl_xor(mx, 16));
      mx = fmaxf(mx, __shfl_xor(mx, 32));
      const float mn = fmaxf(m_run, mx);
      const float alpha = __builtin_amdgcn_exp2f(m_run - mn);
      m_run = mn;
      float sum = 0.f;
#pragma unroll
      for (int n = 0; n < 4; n++)
#pragma unroll
        for (int r = 0; r < 4; r++) {
          float pp = __builtin_amdgcn_exp2f(S[n][r] - mn);
          S[n][r] = pp;
          sum += pp;
        }
      sum += __shfl_xor(sum, 16);
      sum += __shfl_xor(sum, 32);
      l_run = l_run * alpha + sum;
#pragma unroll
      for (int md = 0; md < 8; md++)
#pragma unroll
        for (int r = 0; r < 4; r++) Oa[md][r] *= alpha;
      // P -> LDS [c][key] (keys n*16+quad*4+r are 4 consecutive: one b64)
#pragma unroll
      for (int n = 0; n < 4; n++) {
        short4 pk;
        pk.x = (short)f2bf(S[n][0]); pk.y = (short)f2bf(S[n][1]);
        pk.z = (short)f2bf(S[n][2]); pk.w = (short)f2bf(S[n][3]);
        *(short4*)(Pw + c * 72 + n * 16 + quad * 4) = pk;
      }
      bf16x8 pf[2];
#pragma unroll
      for (int kk2 = 0; kk2 < 2; kk2++)
        pf[kk2] = *(const bf16x8*)(Pw + c * 72 + kk2 * 32 + quad * 8);
      // O^T += V^T * P : rows = d, cols = q-rows
#pragma unroll
      for (int md = 0; md < 8; md++)
#pragma unroll
        for (int kk2 = 0; kk2 < 2; kk2++) {
          bf16x8 vf = *(const bf16x8*)(Vs + kk2 * 4096 + (md * 16 + c) * 32 + quad * 8);
          Oa[md] = __builtin_amdgcn_mfma_f32_16x16x32_bf16(vf, pf[kk2], Oa[md], 0, 0, 0);
        }
    }
    // epilogue: normalize, transpose O^T -> O via per-wave LDS bounce, store
    __syncthreads();    // Ks/Vs now reusable as bounce space
    const float invl = 1.f / l_run;
#pragma unroll
    for (int md = 0; md < 8; md++) {
      short4 ok;
      ok.x = (short)f2bf(Oa[md][0] * invl); ok.y = (short)f2bf(Oa[md][1] * invl);
      ok.z = (short)f2bf(Oa[md][2] * invl); ok.w = (short)f2bf(Oa[md][3] * invl);
      *(short4*)(Bw + c * 136 + md * 16 + quad * 4) = ok;
    }
    const int orow = q0 + wave * 16 + lr;
#pragma unroll
    for (int tt = 0; tt < 4; tt++) {
      bf16x8 ov = *(const bf16x8*)(Bw + lr * 136 + lp * 32 + tt * 8);
      *(bf16x8*)(ob + ((size_t)(b * Q_ + orow) * HQ_ + h) * D_ + lp * 32 + tt * 8) = ov;
    }
  }
}

// ---------------- launcher ----------------
extern "C" void kernel_launch(void* const* d_in, const int* in_sizes, int n_in,
                              void* d_out, int out_size, void* d_ws, size_t ws_size,
                              hipStream_t stream) {
  const int*   positions = (const int*)  d_in[0];
  const float* hidden    = (const float*)d_in[1];
  const float* wqkv      = (const float*)d_in[4];
  const float* wo        = (const float*)d_in[5];
  const float* qnw       = (const float*)d_in[6];
  const float* knw       = (const float*)d_in[7];
  char* ws = (char*)d_ws;
  u16*  hid_bf  = (u16*)(ws);                      // 16,777,216
  u16*  wqkv_bf = (u16*)(ws + 16777216);           // 12,582,912
  u16*  wo_bf   = (u16*)(ws + 29360128);           //  8,388,608
  float* qkv    = (float*)(ws + 37748736);         // 50,331,648
  u16*  q_bf    = (u16*)(ws + 88080384);           // 16,777,216
  u16*  k_bf    = (u16*)(ws + 104857600);          //  4,194,304
  u16*  vt_bf   = (u16*)(ws + 109051904);          //  4,194,304
  u16*  attn_bf = hid_bf;                          // alias: hid_bf dead after GEMM1

  cvt_bf16<<<8192, 256, 0, stream>>>(hidden, hid_bf, 2097152);
  cvt_bf16<<<6144, 256, 0, stream>>>(wqkv, wqkv_bf, 1572864);
  cvt_bf16<<<4096, 256, 0, stream>>>(wo, wo_bf, 1048576);
  gemm_bt<<<dim3(32, 24), 256, 0, stream>>>(hid_bf, wqkv_bf, qkv, 4096, 3072, 2048);
  qk_prep<<<4096, 256, 0, stream>>>(qkv, positions, qnw, knw, q_bf, k_bf);
  v_trans<<<dim3(32, 4, 2), 256, 0, stream>>>(qkv, vt_bf);
  attn_fwd<<<dim3(16, 16, 2), 256, 0, stream>>>(q_bf, k_bf, vt_bf, attn_bf);
  gemm_bt<<<dim3(32, 16), 256, 0, stream>>>(attn_bf, wo_bf, (float*)d_out, 4096, 2048, 2048);
}

// Round 3
// 346.413 us; speedup vs baseline: 1.3136x; 1.0817x over previous
//
#include <hip/hip_runtime.h>

// ---------------- problem constants ----------------
#define B_    2
#define Q_    2048
#define HID_  2048
#define HQ_   16
#define HKV_  4
#define D_    128
#define NQKV  3072          // HQ*D + 2*HKV*D
#define QS_   2048          // q block size in qkv row
#define KVS_  512           // k block size in qkv row
// softmax scale folded into q, in exp2 domain: D^-0.5 * log2(e)
#define QSC_  (0.08838834764831843f * 1.4426950408889634f)
#define LOG2_THETA 19.931568569324174f // log2(1e6)

typedef unsigned short u16;
typedef __attribute__((ext_vector_type(8))) short bf16x8;
typedef __attribute__((ext_vector_type(4))) float f32x4;

__device__ __forceinline__ u16 f2bf(float x) {           // round-nearest-even
  union { float f; unsigned int u; } v; v.f = x;
  unsigned int r = v.u + 0x7FFFu + ((v.u >> 16) & 1u);
  return (u16)(r >> 16);
}
__device__ __forceinline__ u16 f2bf_t(float x) {         // truncate (hot loop)
  union { float f; unsigned int u; } v; v.f = x;
  return (u16)(v.u >> 16);
}

// async global->LDS, 16B per lane; lds must be the wave-uniform base
__device__ __forceinline__ void gl2lds16(u16* lds, const u16* g) {
  __builtin_amdgcn_global_load_lds((const __attribute__((address_space(1))) void*)g,
                                   (__attribute__((address_space(3))) void*)lds,
                                   16, 0, 0);
}

// ---------------- fused fp32 -> bf16 casts (hidden, wqkv, wo) ----------------
#define N4_HID  2097152
#define N4_WQKV 1572864
#define N4_WO   1048576
__global__ __launch_bounds__(256) void cvt_all(const float* __restrict__ h,
                                               const float* __restrict__ wq,
                                               const float* __restrict__ wo,
                                               u16* __restrict__ oh,
                                               u16* __restrict__ owq,
                                               u16* __restrict__ owo) {
  int i = blockIdx.x * 256 + threadIdx.x;
  const float* src; u16* dst; int off;
  if (i < N4_HID)                 { src = h;  dst = oh;  off = i; }
  else if (i < N4_HID + N4_WQKV)  { src = wq; dst = owq; off = i - N4_HID; }
  else                            { src = wo; dst = owo; off = i - N4_HID - N4_WQKV; }
  float4 v = *(const float4*)(src + (size_t)off * 4);
  ushort4 o;
  o.x = f2bf(v.x); o.y = f2bf(v.y); o.z = f2bf(v.z); o.w = f2bf(v.w);
  *(ushort4*)(dst + (size_t)off * 4) = o;
}

// ---------------- bf16 GEMM, C = A * B^T (A: MxK, B: NxK, C: MxN fp32) ------
// LDS chunk-swizzled: physical 16B chunk = (logical + (row>>1)) & 3
__global__ __launch_bounds__(256) void gemm_bt(const u16* __restrict__ A,
                                               const u16* __restrict__ Bw,
                                               float* __restrict__ C,
                                               int M, int N, int K) {
  __shared__ __align__(16) u16 As[128 * 32];
  __shared__ __align__(16) u16 Bs[128 * 32];
  const int tid = threadIdx.x;
  const int wave = tid >> 6, lane = tid & 63;
  const int wm = wave & 1, wn = wave >> 1;
  const int row16 = lane & 15, quad = lane >> 4;
  const int lr = lane >> 2, lp = lane & 3;
  const int lpg = (lp + 4 - ((lr >> 1) & 3)) & 3;          // staging swizzle
  const int swq = (((quad + (row16 >> 1)) & 3)) * 8;       // read swizzle
  const int m0 = blockIdx.x * 128, n0 = blockIdx.y * 128;
  f32x4 acc[4][4] = {};
  for (int k0 = 0; k0 < K; k0 += 32) {
    __syncthreads();
#pragma unroll
    for (int i = 0; i < 2; i++) {
      int r = wave * 16 + i * 64 + lr;
      gl2lds16(As + (size_t)(wave * 64 + i * 256) * 8,
               A + (size_t)(m0 + r) * K + k0 + lpg * 8);
      gl2lds16(Bs + (size_t)(wave * 64 + i * 256) * 8,
               Bw + (size_t)(n0 + r) * K + k0 + lpg * 8);
    }
    __syncthreads();
    bf16x8 af[4], bfr[4];
#pragma unroll
    for (int t = 0; t < 4; t++) {
      af[t]  = *(const bf16x8*)(As + (wm * 64 + t * 16 + row16) * 32 + swq);
      bfr[t] = *(const bf16x8*)(Bs + (wn * 64 + t * 16 + row16) * 32 + swq);
    }
#pragma unroll
    for (int mi = 0; mi < 4; mi++)
#pragma unroll
      for (int ni = 0; ni < 4; ni++)
        acc[mi][ni] = __builtin_amdgcn_mfma_f32_16x16x32_bf16(af[mi], bfr[ni],
                                                              acc[mi][ni], 0, 0, 0);
  }
#pragma unroll
  for (int mi = 0; mi < 4; mi++) {
    int row = m0 + wm * 64 + mi * 16 + quad * 4;
#pragma unroll
    for (int ni = 0; ni < 4; ni++) {
      int col = n0 + wn * 64 + ni * 16 + row16;
#pragma unroll
      for (int r = 0; r < 4; r++)
        C[(size_t)(row + r) * N + col] = acc[mi][ni][r];
    }
  }
}

// ---------------- RMSNorm + RoPE for q,k; write bf16 (B,H,S,D) --------------
__global__ __launch_bounds__(256) void qk_prep(const float* __restrict__ qkv,
                                               const int* __restrict__ pos,
                                               const float* __restrict__ qw,
                                               const float* __restrict__ kw,
                                               u16* __restrict__ qb,
                                               u16* __restrict__ kb) {
  const int row = blockIdx.x;
  const int b = row >> 11, q = row & (Q_ - 1);
  const int wave = threadIdx.x >> 6, lane = threadIdx.x & 63;
  const float p = (float)pos[row];
  const float inv = exp2f(-(float)lane * (LOG2_THETA / 64.f));
  float sn, cs;
  sincosf(p * inv, &sn, &cs);
#pragma unroll
  for (int j = 0; j < 5; j++) {
    const int hh = wave * 5 + j;           // 0..19: 16 q heads then 4 k heads
    const bool isq = hh < 16;
    const int col = isq ? hh * D_ : QS_ + (hh - 16) * D_;
    const float* src = qkv + (size_t)row * NQKV + col;
    float x1 = src[lane], x2 = src[lane + 64];
    float ss = x1 * x1 + x2 * x2;
#pragma unroll
    for (int m = 1; m < 64; m <<= 1) ss += __shfl_xor(ss, m);
    const float rn = rsqrtf(ss * (1.f / 128.f) + 1e-6f);
    const float* w = isq ? qw : kw;
    float xn1 = x1 * rn * w[lane], xn2 = x2 * rn * w[lane + 64];
    float y1 = xn1 * cs - xn2 * sn;
    float y2 = xn2 * cs + xn1 * sn;
    if (isq) { y1 *= QSC_; y2 *= QSC_; }
    u16* dst = isq ? (qb + (((size_t)b * HQ_ + hh) * Q_ + q) * D_)
                   : (kb + (((size_t)b * HKV_ + (hh - 16)) * Q_ + q) * D_);
    dst[lane]      = f2bf(y1);
    dst[lane + 64] = f2bf(y2);
  }
}

// ---------------- V transpose: qkv v-block -> vt (B,HKV,D,S) bf16 -----------
__global__ __launch_bounds__(256) void v_trans(const float* __restrict__ qkv,
                                               u16* __restrict__ vt) {
  __shared__ u16 sv[64][132];
  const int q0 = blockIdx.x * 64, hk = blockIdx.y, b = blockIdx.z;
  const int tid = threadIdx.x;
#pragma unroll
  for (int i = 0; i < 8; i++) {
    int c = tid + i * 256;
    int r = c >> 5, co = (c & 31) * 4;
    float4 v = *(const float4*)(qkv + (size_t)(b * Q_ + q0 + r) * NQKV +
                                QS_ + KVS_ + hk * D_ + co);
    sv[r][co + 0] = f2bf(v.x); sv[r][co + 1] = f2bf(v.y);
    sv[r][co + 2] = f2bf(v.z); sv[r][co + 3] = f2bf(v.w);
  }
  __syncthreads();
#pragma unroll
  for (int i = 0; i < 16; i++) {
    int c = tid + i * 256;
    int d = c >> 5, qq = (c & 31) * 2;
    ushort2 o; o.x = sv[qq][d]; o.y = sv[qq + 1][d];
    *(ushort2*)(vt + ((size_t)(b * HKV_ + hk) * D_ + d) * Q_ + q0 + qq) = o;
  }
}

// ---------------- flash attention, causal, GQA (S^T orientation) ------------
// block = pair of 64-row q-tiles (t, 31-t) -> uniform 33 k-tile iterations.
// Ks/Vs chunk-swizzled (conflict-free b128); Ps stride-72 (already clean).
__global__ __launch_bounds__(256) void attn_fwd(const u16* __restrict__ qb,
                                                const u16* __restrict__ kb,
                                                const u16* __restrict__ vt,
                                                u16* __restrict__ ob) {
  __shared__ __align__(16) u16 lds[8192 + 8192 + 4608];
  u16* Ks = lds;            // [kk 0..3][key 0..63][32]   (swizzled chunks)
  u16* Vs = lds + 8192;     // [kk2 0..1][d 0..127][32]   (swizzled chunks)
  u16* Ps = lds + 16384;    // per-wave [c 0..15][key 0..63], row stride 72
  const int p = blockIdx.x, h = blockIdx.y, b = blockIdx.z;
  const int hk = h >> 2;
  const int tid = threadIdx.x, wave = tid >> 6, lane = tid & 63;
  const int c = lane & 15, quad = lane >> 4;
  const int lr = lane >> 2, lp = lane & 3;
  const int lpg = (lp + 4 - ((lr >> 1) & 3)) & 3;          // staging swizzle
  const int swq = (((quad + (c >> 1)) & 3)) * 8;           // read swizzle
  const u16* qg = qb + ((size_t)b * HQ_ + h) * (size_t)Q_ * D_;
  const u16* kg = kb + ((size_t)b * HKV_ + hk) * (size_t)Q_ * D_;
  const u16* vg = vt + ((size_t)b * HKV_ + hk) * (size_t)D_ * Q_;
  u16* Pw = Ps + wave * 1152;        // 16 rows x 72
  u16* Bw = Ks + wave * 2176;        // bounce: 16 rows x 136 (aliases Ks/Vs)

#pragma unroll 1
  for (int tp = 0; tp < 2; tp++) {
    const int t = tp ? (31 - p) : p;
    const int q0 = t * 64;
    const int qrow = q0 + wave * 16 + c;
    bf16x8 qf[4];
#pragma unroll
    for (int kk = 0; kk < 4; kk++)
      qf[kk] = *(const bf16x8*)(qg + (size_t)qrow * D_ + kk * 32 + quad * 8);
    f32x4 Oa[8] = {};
    float m_run = -1e30f, l_run = 0.f;

#pragma unroll 1
    for (int kt = 0; kt <= t; kt++) {
      __syncthreads();
#pragma unroll
      for (int i = 0; i < 4; i++) {
        gl2lds16(Ks + (size_t)(i * 256 + wave * 64) * 8,
                 kg + ((size_t)kt * 64 + wave * 16 + lr) * D_ + i * 32 + lpg * 8);
        int d = (i & 1) * 64 + wave * 16 + lr;
        gl2lds16(Vs + (size_t)(i * 256 + wave * 64) * 8,
                 vg + (size_t)d * Q_ + kt * 64 + (i >> 1) * 32 + lpg * 8);
      }
      __syncthreads();
      // S^T = K * Q^T : rows = keys, cols = q-rows
      f32x4 S[4];
#pragma unroll
      for (int n = 0; n < 4; n++) {
        f32x4 a = {};
#pragma unroll
        for (int kk = 0; kk < 4; kk++) {
          bf16x8 kf = *(const bf16x8*)(Ks + kk * 2048 + (n * 16 + c) * 32 + swq);
          a = __builtin_amdgcn_mfma_f32_16x16x32_bf16(kf, qf[kk], a, 0, 0, 0);
        }
        S[n] = a;
      }
      if (kt == t) {   // diagonal tile: causal mask (key <= qrow)
#pragma unroll
        for (int n = 0; n < 4; n++)
#pragma unroll
          for (int r = 0; r < 4; r++) {
            int key = kt * 64 + n * 16 + quad * 4 + r;
            if (key > qrow) S[n][r] = -1e30f;
          }
      }
      // online softmax: lane owns one q-row's 16 scores (x4 quad replicas)
      float mx = -1e30f;
#pragma unroll
      for (int n = 0; n < 4; n++)
#pragma unroll
        for (int r = 0; r < 4; r++) mx = fmaxf(mx, S[n][r]);
      mx = fmaxf(mx, __shfl_xor(mx, 16));
      mx = fmaxf(mx, __shfl_xor(mx, 32));
      const float mn = fmaxf(m_run, mx);
      const float alpha = __builtin_amdgcn_exp2f(m_run - mn);
      m_run = mn;
      float sum = 0.f;
#pragma unroll
      for (int n = 0; n < 4; n++)
#pragma unroll
        for (int r = 0; r < 4; r++) {
          float pp = __builtin_amdgcn_exp2f(S[n][r] - mn);
          S[n][r] = pp;
          sum += pp;
        }
      sum += __shfl_xor(sum, 16);
      sum += __shfl_xor(sum, 32);
      l_run = l_run * alpha + sum;
#pragma unroll
      for (int md = 0; md < 8; md++)
#pragma unroll
        for (int r = 0; r < 4; r++) Oa[md][r] *= alpha;
      // P -> LDS [c][key] (keys n*16+quad*4+r are 4 consecutive: one b64)
#pragma unroll
      for (int n = 0; n < 4; n++) {
        short4 pk;
        pk.x = (short)f2bf_t(S[n][0]); pk.y = (short)f2bf_t(S[n][1]);
        pk.z = (short)f2bf_t(S[n][2]); pk.w = (short)f2bf_t(S[n][3]);
        *(short4*)(Pw + c * 72 + n * 16 + quad * 4) = pk;
      }
      bf16x8 pf[2];
#pragma unroll
      for (int kk2 = 0; kk2 < 2; kk2++)
        pf[kk2] = *(const bf16x8*)(Pw + c * 72 + kk2 * 32 + quad * 8);
      // O^T += V^T * P : rows = d, cols = q-rows
#pragma unroll
      for (int md = 0; md < 8; md++)
#pragma unroll
        for (int kk2 = 0; kk2 < 2; kk2++) {
          bf16x8 vf = *(const bf16x8*)(Vs + kk2 * 4096 + (md * 16 + c) * 32 + swq);
          Oa[md] = __builtin_amdgcn_mfma_f32_16x16x32_bf16(vf, pf[kk2], Oa[md], 0, 0, 0);
        }
    }
    // epilogue: normalize, transpose O^T -> O via per-wave LDS bounce, store
    __syncthreads();    // Ks/Vs now reusable as bounce space
    const float invl = 1.f / l_run;
#pragma unroll
    for (int md = 0; md < 8; md++) {
      short4 ok;
      ok.x = (short)f2bf(Oa[md][0] * invl); ok.y = (short)f2bf(Oa[md][1] * invl);
      ok.z = (short)f2bf(Oa[md][2] * invl); ok.w = (short)f2bf(Oa[md][3] * invl);
      *(short4*)(Bw + c * 136 + md * 16 + quad * 4) = ok;
    }
    const int orow = q0 + wave * 16 + lr;
#pragma unroll
    for (int tt = 0; tt < 4; tt++) {
      bf16x8 ov = *(const bf16x8*)(Bw + lr * 136 + lp * 32 + tt * 8);
      *(bf16x8*)(ob + ((size_t)(b * Q_ + orow) * HQ_ + h) * D_ + lp * 32 + tt * 8) = ov;
    }
  }
}

// ---------------- launcher ----------------
extern "C" void kernel_launch(void* const* d_in, const int* in_sizes, int n_in,
                              void* d_out, int out_size, void* d_ws, size_t ws_size,
                              hipStream_t stream) {
  const int*   positions = (const int*)  d_in[0];
  const float* hidden    = (const float*)d_in[1];
  const float* wqkv      = (const float*)d_in[4];
  const float* wo        = (const float*)d_in[5];
  const float* qnw       = (const float*)d_in[6];
  const float* knw       = (const float*)d_in[7];
  char* ws = (char*)d_ws;
  u16*  hid_bf  = (u16*)(ws);                      // 16,777,216
  u16*  wqkv_bf = (u16*)(ws + 16777216);           // 12,582,912
  u16*  wo_bf   = (u16*)(ws + 29360128);           //  8,388,608
  float* qkv    = (float*)(ws + 37748736);         // 50,331,648
  u16*  q_bf    = (u16*)(ws + 88080384);           // 16,777,216
  u16*  k_bf    = (u16*)(ws + 104857600);          //  4,194,304
  u16*  vt_bf   = (u16*)(ws + 109051904);          //  4,194,304
  u16*  attn_bf = hid_bf;                          // alias: hid_bf dead after GEMM1

  cvt_all<<<18432, 256, 0, stream>>>(hidden, wqkv, wo, hid_bf, wqkv_bf, wo_bf);
  gemm_bt<<<dim3(32, 24), 256, 0, stream>>>(hid_bf, wqkv_bf, qkv, 4096, 3072, 2048);
  qk_prep<<<4096, 256, 0, stream>>>(qkv, positions, qnw, knw, q_bf, k_bf);
  v_trans<<<dim3(32, 4, 2), 256, 0, stream>>>(qkv, vt_bf);
  attn_fwd<<<dim3(16, 16, 2), 256, 0, stream>>>(q_bf, k_bf, vt_bf, attn_bf);
  gemm_bt<<<dim3(32, 16), 256, 0, stream>>>(attn_bf, wo_bf, (float*)d_out, 4096, 2048, 2048);
}

// Round 4
// 343.607 us; speedup vs baseline: 1.3243x; 1.0082x over previous
//
#include <hip/hip_runtime.h>

// ---------------- problem constants ----------------
#define B_    2
#define Q_    2048
#define HID_  2048
#define HQ_   16
#define HKV_  4
#define D_    128
// softmax scale folded into q, in exp2 domain: D^-0.5 * log2(e)
#define QSC_  (0.08838834764831843f * 1.4426950408889634f)
#define LOG2_THETA 19.931568569324174f // log2(1e6)

typedef unsigned short u16;
typedef __attribute__((ext_vector_type(8))) short bf16x8;
typedef __attribute__((ext_vector_type(4))) float f32x4;

__device__ __forceinline__ u16 f2bf(float x) {           // round-nearest-even
  union { float f; unsigned int u; } v; v.f = x;
  unsigned int r = v.u + 0x7FFFu + ((v.u >> 16) & 1u);
  return (u16)(r >> 16);
}
__device__ __forceinline__ u16 f2bf_t(float x) {         // truncate (hot loop)
  union { float f; unsigned int u; } v; v.f = x;
  return (u16)(v.u >> 16);
}

// async global->LDS, 16B per lane; lds must be the wave-uniform base
__device__ __forceinline__ void gl2lds16(u16* lds, const u16* g) {
  __builtin_amdgcn_global_load_lds((const __attribute__((address_space(1))) void*)g,
                                   (__attribute__((address_space(3))) void*)lds,
                                   16, 0, 0);
}

// ---------------- fused fp32 -> bf16 casts (hidden, wqkv, wo) ----------------
#define N4_HID  2097152
#define N4_WQKV 1572864
#define N4_WO   1048576
__global__ __launch_bounds__(256) void cvt_all(const float* __restrict__ h,
                                               const float* __restrict__ wq,
                                               const float* __restrict__ wo,
                                               u16* __restrict__ oh,
                                               u16* __restrict__ owq,
                                               u16* __restrict__ owo) {
  int i = blockIdx.x * 256 + threadIdx.x;
  const float* src; u16* dst; int off;
  if (i < N4_HID)                 { src = h;  dst = oh;  off = i; }
  else if (i < N4_HID + N4_WQKV)  { src = wq; dst = owq; off = i - N4_HID; }
  else                            { src = wo; dst = owo; off = i - N4_HID - N4_WQKV; }
  float4 v = *(const float4*)(src + (size_t)off * 4);
  ushort4 o;
  o.x = f2bf(v.x); o.y = f2bf(v.y); o.z = f2bf(v.z); o.w = f2bf(v.w);
  *(ushort4*)(dst + (size_t)off * 4) = o;
}

// ---------------- RoPE cos/sin table: rope[(b*Q+q)*64 + d] = {cos, sin} -----
__global__ __launch_bounds__(256) void rope_tab(const int* __restrict__ pos,
                                                float* __restrict__ rope) {
  int i = blockIdx.x * 256 + threadIdx.x;     // over B*Q*64
  int d = i & 63, row = i >> 6;
  float p = (float)pos[row];
  float inv = exp2f(-(float)d * (LOG2_THETA / 64.f));
  float sn, cn;
  sincosf(p * inv, &sn, &cn);
  float2* o = (float2*)rope;
  o[i] = make_float2(cn, sn);
}

// ---------------- fused QKV GEMM + RMSNorm + RoPE + layout ------------------
// C = hidden * wqkv^T, 128x128 tiles; each col-tile is exactly one head.
// Wave wv owns rows [wv*32, wv*32+32) x all 128 cols (acc[2][8]) so RMSNorm
// and RoPE are wave-local in the epilogue. Outputs:
//   q_bf (B,HQ,S,D) bf16 (norm+rope+scale), k_bf (B,HKV,S,D) bf16 (norm+rope),
//   vt   (B,HKV,D,S) bf16 (transposed).
__global__ __launch_bounds__(256) void gemm_qkv(const u16* __restrict__ A,
                                                const u16* __restrict__ Bw,
                                                const float* __restrict__ rope,
                                                const float* __restrict__ qw,
                                                const float* __restrict__ kw,
                                                u16* __restrict__ qb,
                                                u16* __restrict__ kb,
                                                u16* __restrict__ vt) {
  __shared__ __align__(16) u16 lds[12288];    // staging 16KB; epilogue reuses
  u16* As = lds;
  u16* Bs = lds + 4096;
  const int tid = threadIdx.x;
  const int wv = tid >> 6, lane = tid & 63;
  const int c = lane & 15, quad = lane >> 4;
  const int lr = lane >> 2, lp = lane & 3;
  const int lpg = (lp + 4 - ((lr >> 1) & 3)) & 3;          // staging swizzle
  const int swq = ((quad + (c >> 1)) & 3) * 8;             // read swizzle
  const int m0 = blockIdx.x * 128;
  const int by = blockIdx.y;
  const int n0 = by * 128;
  f32x4 acc[2][8] = {};
  for (int k0 = 0; k0 < HID_; k0 += 32) {
    __syncthreads();
#pragma unroll
    for (int i = 0; i < 2; i++) {
      int r = wv * 16 + i * 64 + lr;
      gl2lds16(As + (size_t)(wv * 64 + i * 256) * 8,
               A + (size_t)(m0 + r) * HID_ + k0 + lpg * 8);
      gl2lds16(Bs + (size_t)(wv * 64 + i * 256) * 8,
               Bw + (size_t)(n0 + r) * HID_ + k0 + lpg * 8);
    }
    __syncthreads();
    bf16x8 af[2], bfr[8];
#pragma unroll
    for (int mi = 0; mi < 2; mi++)
      af[mi] = *(const bf16x8*)(As + (wv * 32 + mi * 16 + c) * 32 + swq);
#pragma unroll
    for (int ni = 0; ni < 8; ni++)
      bfr[ni] = *(const bf16x8*)(Bs + (ni * 16 + c) * 32 + swq);
#pragma unroll
    for (int mi = 0; mi < 2; mi++)
#pragma unroll
      for (int ni = 0; ni < 8; ni++)
        acc[mi][ni] = __builtin_amdgcn_mfma_f32_16x16x32_bf16(af[mi], bfr[ni],
                                                              acc[mi][ni], 0, 0, 0);
  }
  __syncthreads();                            // LDS now reusable by epilogue

  if (by < 20) {
    // ---- q/k head: RMSNorm + RoPE + (q) scale, then bounce-store ----
    const bool isq = by < 16;
    const float* w = isq ? qw : kw;
    const float osc = isq ? QSC_ : 1.f;
    float wl[8];
#pragma unroll
    for (int ni = 0; ni < 8; ni++) wl[ni] = w[ni * 16 + c];
    u16 ob[2][4][8];
#pragma unroll
    for (int mi = 0; mi < 2; mi++)
#pragma unroll
      for (int r = 0; r < 4; r++) {
        const int row = m0 + wv * 32 + mi * 16 + quad * 4 + r;
        const int q = row & (Q_ - 1), b = row >> 11;
        float ss = 0.f;
#pragma unroll
        for (int ni = 0; ni < 8; ni++) ss += acc[mi][ni][r] * acc[mi][ni][r];
        ss += __shfl_xor(ss, 1); ss += __shfl_xor(ss, 2);
        ss += __shfl_xor(ss, 4); ss += __shfl_xor(ss, 8);
        const float rn = rsqrtf(ss * (1.f / 128.f) + 1e-6f) * osc;
#pragma unroll
        for (int ni = 0; ni < 4; ni++) {
          float2 cssn = *(const float2*)(rope +
              ((size_t)(b * Q_ + q) * 64 + ni * 16 + c) * 2);
          float x1 = acc[mi][ni][r]     * wl[ni]     * rn;
          float x2 = acc[mi][ni + 4][r] * wl[ni + 4] * rn;
          ob[mi][r][ni]     = f2bf(x1 * cssn.x - x2 * cssn.y);
          ob[mi][r][ni + 4] = f2bf(x2 * cssn.x + x1 * cssn.y);
        }
      }
    u16* dstbuf = isq ? qb : kb;
    const int hbase = isq ? (HQ_ * 0 + by) : (by - 16);
    const int nheads = isq ? HQ_ : HKV_;
#pragma unroll
    for (int ph = 0; ph < 2; ph++) {
      if (ph) __syncthreads();
      if ((wv >> 1) == ph) {
#pragma unroll
        for (int mi = 0; mi < 2; mi++)
#pragma unroll
          for (int r = 0; r < 4; r++)
#pragma unroll
            for (int ni = 0; ni < 8; ni++)
              lds[((wv & 1) * 32 + mi * 16 + quad * 4 + r) * 132 + ni * 16 + c] =
                  ob[mi][r][ni];
      }
      __syncthreads();
      const int rowg = m0 + ph * 64 + (tid >> 2);
      const int q = rowg & (Q_ - 1), b = rowg >> 11;
      u16* dst = dstbuf + (((size_t)(b * nheads) + hbase) * Q_ + q) * D_ + (tid & 3) * 32;
      const u16* srcl = lds + (tid >> 2) * 132 + (tid & 3) * 32;
#pragma unroll
      for (int j = 0; j < 4; j++)
        *(bf16x8*)(dst + j * 8) = *(const bf16x8*)(srcl + j * 8);
    }
  } else {
    // ---- v head: transpose to (B,HKV,D,S) via per-wave bounce ----
    const int hk = by - 20;
    const int bb = m0 >> 11, q0 = m0 & (Q_ - 1);
    u16* vw = lds + wv * 3072;               // 128 d x 16 s, stride 24 u16
#pragma unroll
    for (int mi = 0; mi < 2; mi++) {
      if (mi) __syncthreads();
#pragma unroll
      for (int ni = 0; ni < 8; ni++) {
        short4 pv;
        pv.x = (short)f2bf(acc[mi][ni][0]); pv.y = (short)f2bf(acc[mi][ni][1]);
        pv.z = (short)f2bf(acc[mi][ni][2]); pv.w = (short)f2bf(acc[mi][ni][3]);
        *(short4*)(vw + (ni * 16 + c) * 24 + quad * 4) = pv;
      }
      __syncthreads();
#pragma unroll
      for (int it = 0; it < 2; it++) {
        const int d = it * 64 + lane;
        const u16* src = vw + d * 24;
        u16* dst = vt + (((size_t)(bb * HKV_) + hk) * D_ + d) * Q_ +
                   q0 + wv * 32 + mi * 16;
        *(bf16x8*)(dst)     = *(const bf16x8*)(src);
        *(bf16x8*)(dst + 8) = *(const bf16x8*)(src + 8);
      }
    }
  }
}

// ---------------- bf16 GEMM, C = A * B^T (A: MxK, B: NxK, C: MxN fp32) ------
__global__ __launch_bounds__(256) void gemm_bt(const u16* __restrict__ A,
                                               const u16* __restrict__ Bw,
                                               float* __restrict__ C,
                                               int M, int N, int K) {
  __shared__ __align__(16) u16 As[128 * 32];
  __shared__ __align__(16) u16 Bs[128 * 32];
  const int tid = threadIdx.x;
  const int wave = tid >> 6, lane = tid & 63;
  const int wm = wave & 1, wn = wave >> 1;
  const int row16 = lane & 15, quad = lane >> 4;
  const int lr = lane >> 2, lp = lane & 3;
  const int lpg = (lp + 4 - ((lr >> 1) & 3)) & 3;
  const int swq = ((quad + (row16 >> 1)) & 3) * 8;
  const int m0 = blockIdx.x * 128, n0 = blockIdx.y * 128;
  f32x4 acc[4][4] = {};
  for (int k0 = 0; k0 < K; k0 += 32) {
    __syncthreads();
#pragma unroll
    for (int i = 0; i < 2; i++) {
      int r = wave * 16 + i * 64 + lr;
      gl2lds16(As + (size_t)(wave * 64 + i * 256) * 8,
               A + (size_t)(m0 + r) * K + k0 + lpg * 8);
      gl2lds16(Bs + (size_t)(wave * 64 + i * 256) * 8,
               Bw + (size_t)(n0 + r) * K + k0 + lpg * 8);
    }
    __syncthreads();
    bf16x8 af[4], bfr[4];
#pragma unroll
    for (int t = 0; t < 4; t++) {
      af[t]  = *(const bf16x8*)(As + (wm * 64 + t * 16 + row16) * 32 + swq);
      bfr[t] = *(const bf16x8*)(Bs + (wn * 64 + t * 16 + row16) * 32 + swq);
    }
#pragma unroll
    for (int mi = 0; mi < 4; mi++)
#pragma unroll
      for (int ni = 0; ni < 4; ni++)
        acc[mi][ni] = __builtin_amdgcn_mfma_f32_16x16x32_bf16(af[mi], bfr[ni],
                                                              acc[mi][ni], 0, 0, 0);
  }
#pragma unroll
  for (int mi = 0; mi < 4; mi++) {
    int row = m0 + wm * 64 + mi * 16 + quad * 4;
#pragma unroll
    for (int ni = 0; ni < 4; ni++) {
      int col = n0 + wn * 64 + ni * 16 + row16;
#pragma unroll
      for (int r = 0; r < 4; r++)
        C[(size_t)(row + r) * N + col] = acc[mi][ni][r];
    }
  }
}

// ---------------- flash attention, causal, GQA (S^T orientation) ------------
__global__ __launch_bounds__(256) void attn_fwd(const u16* __restrict__ qb,
                                                const u16* __restrict__ kb,
                                                const u16* __restrict__ vt,
                                                u16* __restrict__ ob) {
  __shared__ __align__(16) u16 lds[8192 + 8192 + 4608];
  u16* Ks = lds;            // [kk 0..3][key 0..63][32]   (swizzled chunks)
  u16* Vs = lds + 8192;     // [kk2 0..1][d 0..127][32]   (swizzled chunks)
  u16* Ps = lds + 16384;    // per-wave [c 0..15][key 0..63], row stride 72
  const int p = blockIdx.x, h = blockIdx.y, b = blockIdx.z;
  const int hk = h >> 2;
  const int tid = threadIdx.x, wave = tid >> 6, lane = tid & 63;
  const int c = lane & 15, quad = lane >> 4;
  const int lr = lane >> 2, lp = lane & 3;
  const int lpg = (lp + 4 - ((lr >> 1) & 3)) & 3;
  const int swq = ((quad + (c >> 1)) & 3) * 8;
  const u16* qg = qb + ((size_t)b * HQ_ + h) * (size_t)Q_ * D_;
  const u16* kg = kb + ((size_t)b * HKV_ + hk) * (size_t)Q_ * D_;
  const u16* vg = vt + ((size_t)b * HKV_ + hk) * (size_t)D_ * Q_;
  u16* Pw = Ps + wave * 1152;
  u16* Bw = Ks + wave * 2176;

#pragma unroll 1
  for (int tp = 0; tp < 2; tp++) {
    const int t = tp ? (31 - p) : p;
    const int q0 = t * 64;
    const int qrow = q0 + wave * 16 + c;
    bf16x8 qf[4];
#pragma unroll
    for (int kk = 0; kk < 4; kk++)
      qf[kk] = *(const bf16x8*)(qg + (size_t)qrow * D_ + kk * 32 + quad * 8);
    f32x4 Oa[8] = {};
    float m_run = -1e30f, l_run = 0.f;

#pragma unroll 1
    for (int kt = 0; kt <= t; kt++) {
      __syncthreads();
#pragma unroll
      for (int i = 0; i < 4; i++) {
        gl2lds16(Ks + (size_t)(i * 256 + wave * 64) * 8,
                 kg + ((size_t)kt * 64 + wave * 16 + lr) * D_ + i * 32 + lpg * 8);
        int d = (i & 1) * 64 + wave * 16 + lr;
        gl2lds16(Vs + (size_t)(i * 256 + wave * 64) * 8,
                 vg + (size_t)d * Q_ + kt * 64 + (i >> 1) * 32 + lpg * 8);
      }
      __syncthreads();
      f32x4 S[4];
#pragma unroll
      for (int n = 0; n < 4; n++) {
        f32x4 a = {};
#pragma unroll
        for (int kk = 0; kk < 4; kk++) {
          bf16x8 kf = *(const bf16x8*)(Ks + kk * 2048 + (n * 16 + c) * 32 + swq);
          a = __builtin_amdgcn_mfma_f32_16x16x32_bf16(kf, qf[kk], a, 0, 0, 0);
        }
        S[n] = a;
      }
      if (kt == t) {
#pragma unroll
        for (int n = 0; n < 4; n++)
#pragma unroll
          for (int r = 0; r < 4; r++) {
            int key = kt * 64 + n * 16 + quad * 4 + r;
            if (key > qrow) S[n][r] = -1e30f;
          }
      }
      float mx = -1e30f;
#pragma unroll
      for (int n = 0; n < 4; n++)
#pragma unroll
        for (int r = 0; r < 4; r++) mx = fmaxf(mx, S[n][r]);
      mx = fmaxf(mx, __shfl_xor(mx, 16));
      mx = fmaxf(mx, __shfl_xor(mx, 32));
      const float mn = fmaxf(m_run, mx);
      const float alpha = __builtin_amdgcn_exp2f(m_run - mn);
      m_run = mn;
      float sum = 0.f;
#pragma unroll
      for (int n = 0; n < 4; n++)
#pragma unroll
        for (int r = 0; r < 4; r++) {
          float pp = __builtin_amdgcn_exp2f(S[n][r] - mn);
          S[n][r] = pp;
          sum += pp;
        }
      sum += __shfl_xor(sum, 16);
      sum += __shfl_xor(sum, 32);
      l_run = l_run * alpha + sum;
#pragma unroll
      for (int md = 0; md < 8; md++)
#pragma unroll
        for (int r = 0; r < 4; r++) Oa[md][r] *= alpha;
#pragma unroll
      for (int n = 0; n < 4; n++) {
        short4 pk;
        pk.x = (short)f2bf_t(S[n][0]); pk.y = (short)f2bf_t(S[n][1]);
        pk.z = (short)f2bf_t(S[n][2]); pk.w = (short)f2bf_t(S[n][3]);
        *(short4*)(Pw + c * 72 + n * 16 + quad * 4) = pk;
      }
      bf16x8 pf[2];
#pragma unroll
      for (int kk2 = 0; kk2 < 2; kk2++)
        pf[kk2] = *(const bf16x8*)(Pw + c * 72 + kk2 * 32 + quad * 8);
#pragma unroll
      for (int md = 0; md < 8; md++)
#pragma unroll
        for (int kk2 = 0; kk2 < 2; kk2++) {
          bf16x8 vf = *(const bf16x8*)(Vs + kk2 * 4096 + (md * 16 + c) * 32 + swq);
          Oa[md] = __builtin_amdgcn_mfma_f32_16x16x32_bf16(vf, pf[kk2], Oa[md], 0, 0, 0);
        }
    }
    __syncthreads();
    const float invl = 1.f / l_run;
#pragma unroll
    for (int md = 0; md < 8; md++) {
      short4 ok;
      ok.x = (short)f2bf(Oa[md][0] * invl); ok.y = (short)f2bf(Oa[md][1] * invl);
      ok.z = (short)f2bf(Oa[md][2] * invl); ok.w = (short)f2bf(Oa[md][3] * invl);
      *(short4*)(Bw + c * 136 + md * 16 + quad * 4) = ok;
    }
    const int orow = q0 + wave * 16 + lr;
#pragma unroll
    for (int tt = 0; tt < 4; tt++) {
      bf16x8 ov = *(const bf16x8*)(Bw + lr * 136 + lp * 32 + tt * 8);
      *(bf16x8*)(ob + ((size_t)(b * Q_ + orow) * HQ_ + h) * D_ + lp * 32 + tt * 8) = ov;
    }
  }
}

// ---------------- launcher ----------------
extern "C" void kernel_launch(void* const* d_in, const int* in_sizes, int n_in,
                              void* d_out, int out_size, void* d_ws, size_t ws_size,
                              hipStream_t stream) {
  const int*   positions = (const int*)  d_in[0];
  const float* hidden    = (const float*)d_in[1];
  const float* wqkv      = (const float*)d_in[4];
  const float* wo        = (const float*)d_in[5];
  const float* qnw       = (const float*)d_in[6];
  const float* knw       = (const float*)d_in[7];
  char* ws = (char*)d_ws;
  u16*   hid_bf  = (u16*)(ws);                     // 16,777,216
  u16*   wqkv_bf = (u16*)(ws + 16777216);          // 12,582,912
  u16*   wo_bf   = (u16*)(ws + 29360128);          //  8,388,608
  u16*   q_bf    = (u16*)(ws + 37748736);          // 16,777,216
  u16*   k_bf    = (u16*)(ws + 54525952);          //  4,194,304
  u16*   vt_bf   = (u16*)(ws + 58720256);          //  4,194,304
  float* rope    = (float*)(ws + 62914560);        //  2,097,152
  u16*   attn_bf = hid_bf;                         // alias: dead after gemm_qkv

  cvt_all<<<18432, 256, 0, stream>>>(hidden, wqkv, wo, hid_bf, wqkv_bf, wo_bf);
  rope_tab<<<1024, 256, 0, stream>>>(positions, rope);
  gemm_qkv<<<dim3(32, 24), 256, 0, stream>>>(hid_bf, wqkv_bf, rope, qnw, knw,
                                             q_bf, k_bf, vt_bf);
  attn_fwd<<<dim3(16, 16, 2), 256, 0, stream>>>(q_bf, k_bf, vt_bf, attn_bf);
  gemm_bt<<<dim3(32, 16), 256, 0, stream>>>(attn_bf, wo_bf, (float*)d_out, 4096, 2048, 2048);
}

// Round 5
// 336.871 us; speedup vs baseline: 1.3508x; 1.0200x over previous
//
#include <hip/hip_runtime.h>

// ---------------- problem constants ----------------
#define B_    2
#define Q_    2048
#define HID_  2048
#define HQ_   16
#define HKV_  4
#define D_    128
// softmax scale folded into q, in exp2 domain: D^-0.5 * log2(e)
#define QSC_  (0.08838834764831843f * 1.4426950408889634f)
#define LOG2_THETA 19.931568569324174f // log2(1e6)
// fixed softmax max: |score*log2e| <= sqrt(128)*1.4427 = 16.33 < 20 (RMSNorm'd q,k)
#define FMAX_ 20.0f

typedef unsigned short u16;
typedef __attribute__((ext_vector_type(8))) short bf16x8;
typedef __attribute__((ext_vector_type(4))) float f32x4;

__device__ __forceinline__ u16 f2bf(float x) {           // round-nearest-even
  union { float f; unsigned int u; } v; v.f = x;
  unsigned int r = v.u + 0x7FFFu + ((v.u >> 16) & 1u);
  return (u16)(r >> 16);
}
__device__ __forceinline__ u16 f2bf_t(float x) {         // truncate (hot loop)
  union { float f; unsigned int u; } v; v.f = x;
  return (u16)(v.u >> 16);
}

// async global->LDS, 16B per lane; lds must be the wave-uniform base
__device__ __forceinline__ void gl2lds16(u16* lds, const u16* g) {
  __builtin_amdgcn_global_load_lds((const __attribute__((address_space(1))) void*)g,
                                   (__attribute__((address_space(3))) void*)lds,
                                   16, 0, 0);
}

// ------- fused fp32->bf16 casts (hidden, wqkv, wo) + RoPE cos/sin table -----
#define N4_HID  2097152
#define N4_WQKV 1572864
#define N4_WO   1048576
#define N4_ALL  (N4_HID + N4_WQKV + N4_WO)     // 4718592 = 18432*256
#define NROPE   (B_ * Q_ * 64)                 // 262144  = 1024*256
__global__ __launch_bounds__(256) void cvt_all(const float* __restrict__ h,
                                               const float* __restrict__ wq,
                                               const float* __restrict__ wo,
                                               const int* __restrict__ pos,
                                               u16* __restrict__ oh,
                                               u16* __restrict__ owq,
                                               u16* __restrict__ owo,
                                               float* __restrict__ rope) {
  int i = blockIdx.x * 256 + threadIdx.x;
  if (i >= N4_ALL) {                            // RoPE table part
    int j = i - N4_ALL;                         // < NROPE
    int d = j & 63, row = j >> 6;
    float p = (float)pos[row];
    float inv = exp2f(-(float)d * (LOG2_THETA / 64.f));
    float sn, cn;
    sincosf(p * inv, &sn, &cn);
    ((float2*)rope)[j] = make_float2(cn, sn);
    return;
  }
  const float* src; u16* dst; int off;
  if (i < N4_HID)                 { src = h;  dst = oh;  off = i; }
  else if (i < N4_HID + N4_WQKV)  { src = wq; dst = owq; off = i - N4_HID; }
  else                            { src = wo; dst = owo; off = i - N4_HID - N4_WQKV; }
  float4 v = *(const float4*)(src + (size_t)off * 4);
  ushort4 o;
  o.x = f2bf(v.x); o.y = f2bf(v.y); o.z = f2bf(v.z); o.w = f2bf(v.w);
  *(ushort4*)(dst + (size_t)off * 4) = o;
}

// ---------------- fused QKV GEMM + RMSNorm + RoPE + layout ------------------
__global__ __launch_bounds__(256) void gemm_qkv(const u16* __restrict__ A,
                                                const u16* __restrict__ Bw,
                                                const float* __restrict__ rope,
                                                const float* __restrict__ qw,
                                                const float* __restrict__ kw,
                                                u16* __restrict__ qb,
                                                u16* __restrict__ kb,
                                                u16* __restrict__ vt) {
  __shared__ __align__(16) u16 lds[12288];    // staging 16KB; epilogue reuses
  u16* As = lds;
  u16* Bs = lds + 4096;
  const int tid = threadIdx.x;
  const int wv = tid >> 6, lane = tid & 63;
  const int c = lane & 15, quad = lane >> 4;
  const int lr = lane >> 2, lp = lane & 3;
  const int lpg = (lp + 4 - ((lr >> 1) & 3)) & 3;          // staging swizzle
  const int swq = ((quad + (c >> 1)) & 3) * 8;             // read swizzle
  const int m0 = blockIdx.x * 128;
  const int by = blockIdx.y;
  const int n0 = by * 128;
  f32x4 acc[2][8] = {};
  for (int k0 = 0; k0 < HID_; k0 += 32) {
    __syncthreads();
#pragma unroll
    for (int i = 0; i < 2; i++) {
      int r = wv * 16 + i * 64 + lr;
      gl2lds16(As + (size_t)(wv * 64 + i * 256) * 8,
               A + (size_t)(m0 + r) * HID_ + k0 + lpg * 8);
      gl2lds16(Bs + (size_t)(wv * 64 + i * 256) * 8,
               Bw + (size_t)(n0 + r) * HID_ + k0 + lpg * 8);
    }
    __syncthreads();
    bf16x8 af[2], bfr[8];
#pragma unroll
    for (int mi = 0; mi < 2; mi++)
      af[mi] = *(const bf16x8*)(As + (wv * 32 + mi * 16 + c) * 32 + swq);
#pragma unroll
    for (int ni = 0; ni < 8; ni++)
      bfr[ni] = *(const bf16x8*)(Bs + (ni * 16 + c) * 32 + swq);
#pragma unroll
    for (int mi = 0; mi < 2; mi++)
#pragma unroll
      for (int ni = 0; ni < 8; ni++)
        acc[mi][ni] = __builtin_amdgcn_mfma_f32_16x16x32_bf16(af[mi], bfr[ni],
                                                              acc[mi][ni], 0, 0, 0);
  }
  __syncthreads();                            // LDS now reusable by epilogue

  if (by < 20) {
    // ---- q/k head: RMSNorm + RoPE + (q) scale, computed straight into LDS --
    const bool isq = by < 16;
    const float* w = isq ? qw : kw;
    const float osc = isq ? QSC_ : 1.f;
    float wl[8];
#pragma unroll
    for (int ni = 0; ni < 8; ni++) wl[ni] = w[ni * 16 + c];
    u16* dstbuf = isq ? qb : kb;
    const int hbase = isq ? by : (by - 16);
    const int nheads = isq ? HQ_ : HKV_;
#pragma unroll
    for (int ph = 0; ph < 2; ph++) {
      if (ph) __syncthreads();
      if ((wv >> 1) == ph) {
#pragma unroll
        for (int mi = 0; mi < 2; mi++)
#pragma unroll
          for (int r = 0; r < 4; r++) {
            const int row = m0 + wv * 32 + mi * 16 + quad * 4 + r;
            const int q = row & (Q_ - 1), b = row >> 11;
            float ss = 0.f;
#pragma unroll
            for (int ni = 0; ni < 8; ni++) ss += acc[mi][ni][r] * acc[mi][ni][r];
            ss += __shfl_xor(ss, 1); ss += __shfl_xor(ss, 2);
            ss += __shfl_xor(ss, 4); ss += __shfl_xor(ss, 8);
            const float rn = rsqrtf(ss * (1.f / 128.f) + 1e-6f) * osc;
            u16* lrow = lds + ((wv & 1) * 32 + mi * 16 + quad * 4 + r) * 132;
#pragma unroll
            for (int ni = 0; ni < 4; ni++) {
              float2 cssn = *(const float2*)(rope +
                  ((size_t)(b * Q_ + q) * 64 + ni * 16 + c) * 2);
              float x1 = acc[mi][ni][r]     * wl[ni]     * rn;
              float x2 = acc[mi][ni + 4][r] * wl[ni + 4] * rn;
              lrow[ni * 16 + c]       = f2bf(x1 * cssn.x - x2 * cssn.y);
              lrow[(ni + 4) * 16 + c] = f2bf(x2 * cssn.x + x1 * cssn.y);
            }
          }
      }
      __syncthreads();
      const int rowg = m0 + ph * 64 + (tid >> 2);
      const int q = rowg & (Q_ - 1), b = rowg >> 11;
      u16* dst = dstbuf + (((size_t)(b * nheads) + hbase) * Q_ + q) * D_ + (tid & 3) * 32;
      const u16* srcl = lds + (tid >> 2) * 132 + (tid & 3) * 32;
#pragma unroll
      for (int j = 0; j < 4; j++)
        *(bf16x8*)(dst + j * 8) = *(const bf16x8*)(srcl + j * 8);
    }
  } else {
    // ---- v head: transpose to (B,HKV,D,S) via per-wave bounce ----
    const int hk = by - 20;
    const int bb = m0 >> 11, q0 = m0 & (Q_ - 1);
    u16* vw = lds + wv * 3072;               // 128 d x 16 s, stride 24 u16
#pragma unroll
    for (int mi = 0; mi < 2; mi++) {
      if (mi) __syncthreads();
#pragma unroll
      for (int ni = 0; ni < 8; ni++) {
        short4 pv;
        pv.x = (short)f2bf(acc[mi][ni][0]); pv.y = (short)f2bf(acc[mi][ni][1]);
        pv.z = (short)f2bf(acc[mi][ni][2]); pv.w = (short)f2bf(acc[mi][ni][3]);
        *(short4*)(vw + (ni * 16 + c) * 24 + quad * 4) = pv;
      }
      __syncthreads();
#pragma unroll
      for (int it = 0; it < 2; it++) {
        const int d = it * 64 + lane;
        const u16* src = vw + d * 24;
        u16* dst = vt + (((size_t)(bb * HKV_) + hk) * D_ + d) * Q_ +
                   q0 + wv * 32 + mi * 16;
        *(bf16x8*)(dst)     = *(const bf16x8*)(src);
        *(bf16x8*)(dst + 8) = *(const bf16x8*)(src + 8);
      }
    }
  }
}

// ---------------- bf16 GEMM, C = A * B^T (A: MxK, B: NxK, C: MxN fp32) ------
__global__ __launch_bounds__(256) void gemm_bt(const u16* __restrict__ A,
                                               const u16* __restrict__ Bw,
                                               float* __restrict__ C,
                                               int M, int N, int K) {
  __shared__ __align__(16) u16 As[128 * 32];
  __shared__ __align__(16) u16 Bs[128 * 32];
  const int tid = threadIdx.x;
  const int wave = tid >> 6, lane = tid & 63;
  const int wm = wave & 1, wn = wave >> 1;
  const int row16 = lane & 15, quad = lane >> 4;
  const int lr = lane >> 2, lp = lane & 3;
  const int lpg = (lp + 4 - ((lr >> 1) & 3)) & 3;
  const int swq = ((quad + (row16 >> 1)) & 3) * 8;
  const int m0 = blockIdx.x * 128, n0 = blockIdx.y * 128;
  f32x4 acc[4][4] = {};
  for (int k0 = 0; k0 < K; k0 += 32) {
    __syncthreads();
#pragma unroll
    for (int i = 0; i < 2; i++) {
      int r = wave * 16 + i * 64 + lr;
      gl2lds16(As + (size_t)(wave * 64 + i * 256) * 8,
               A + (size_t)(m0 + r) * K + k0 + lpg * 8);
      gl2lds16(Bs + (size_t)(wave * 64 + i * 256) * 8,
               Bw + (size_t)(n0 + r) * K + k0 + lpg * 8);
    }
    __syncthreads();
    bf16x8 af[4], bfr[4];
#pragma unroll
    for (int t = 0; t < 4; t++) {
      af[t]  = *(const bf16x8*)(As + (wm * 64 + t * 16 + row16) * 32 + swq);
      bfr[t] = *(const bf16x8*)(Bs + (wn * 64 + t * 16 + row16) * 32 + swq);
    }
#pragma unroll
    for (int mi = 0; mi < 4; mi++)
#pragma unroll
      for (int ni = 0; ni < 4; ni++)
        acc[mi][ni] = __builtin_amdgcn_mfma_f32_16x16x32_bf16(af[mi], bfr[ni],
                                                              acc[mi][ni], 0, 0, 0);
  }
#pragma unroll
  for (int mi = 0; mi < 4; mi++) {
    int row = m0 + wm * 64 + mi * 16 + quad * 4;
#pragma unroll
    for (int ni = 0; ni < 4; ni++) {
      int col = n0 + wn * 64 + ni * 16 + row16;
#pragma unroll
      for (int r = 0; r < 4; r++)
        C[(size_t)(row + r) * N + col] = acc[mi][ni][r];
    }
  }
}

// ------ flash attention, causal, GQA; fixed-max softmax (RMSNorm bound) -----
// block = pair of 64-row q-tiles (t, 31-t) -> uniform 33 k-tile iterations.
// S^T = K*Q^T with C init = -FMAX_; p = exp2(S) directly (no running max,
// no rescale); l accumulated per-lane, reduced once per strip.
__global__ __launch_bounds__(256) void attn_fwd(const u16* __restrict__ qb,
                                                const u16* __restrict__ kb,
                                                const u16* __restrict__ vt,
                                                u16* __restrict__ ob) {
  __shared__ __align__(16) u16 lds[8192 + 8192 + 4608];
  u16* Ks = lds;            // [kk 0..3][key 0..63][32]   (swizzled chunks)
  u16* Vs = lds + 8192;     // [kk2 0..1][d 0..127][32]   (swizzled chunks)
  u16* Ps = lds + 16384;    // per-wave [c 0..15][key 0..63], row stride 72
  const int p = blockIdx.x, h = blockIdx.y, b = blockIdx.z;
  const int hk = h >> 2;
  const int tid = threadIdx.x, wave = tid >> 6, lane = tid & 63;
  const int c = lane & 15, quad = lane >> 4;
  const int lr = lane >> 2, lp = lane & 3;
  const int lpg = (lp + 4 - ((lr >> 1) & 3)) & 3;
  const int swq = ((quad + (c >> 1)) & 3) * 8;
  const u16* qg = qb + ((size_t)b * HQ_ + h) * (size_t)Q_ * D_;
  const u16* kg = kb + ((size_t)b * HKV_ + hk) * (size_t)Q_ * D_;
  const u16* vg = vt + ((size_t)b * HKV_ + hk) * (size_t)D_ * Q_;
  u16* Pw = Ps + wave * 1152;
  u16* Bw = Ks + wave * 2176;

#pragma unroll 1
  for (int tp = 0; tp < 2; tp++) {
    const int t = tp ? (31 - p) : p;
    const int q0 = t * 64;
    const int qrow = q0 + wave * 16 + c;
    bf16x8 qf[4];
#pragma unroll
    for (int kk = 0; kk < 4; kk++)
      qf[kk] = *(const bf16x8*)(qg + (size_t)qrow * D_ + kk * 32 + quad * 8);
    f32x4 Oa[8] = {};
    float l_acc = 0.f;

#pragma unroll 1
    for (int kt = 0; kt <= t; kt++) {
      __syncthreads();
#pragma unroll
      for (int i = 0; i < 4; i++) {
        gl2lds16(Ks + (size_t)(i * 256 + wave * 64) * 8,
                 kg + ((size_t)kt * 64 + wave * 16 + lr) * D_ + i * 32 + lpg * 8);
        int d = (i & 1) * 64 + wave * 16 + lr;
        gl2lds16(Vs + (size_t)(i * 256 + wave * 64) * 8,
                 vg + (size_t)d * Q_ + kt * 64 + (i >> 1) * 32 + lpg * 8);
      }
      __syncthreads();
      f32x4 S[4];
#pragma unroll
      for (int n = 0; n < 4; n++) {
        f32x4 a = {-FMAX_, -FMAX_, -FMAX_, -FMAX_};   // bias folded into C
#pragma unroll
        for (int kk = 0; kk < 4; kk++) {
          bf16x8 kf = *(const bf16x8*)(Ks + kk * 2048 + (n * 16 + c) * 32 + swq);
          a = __builtin_amdgcn_mfma_f32_16x16x32_bf16(kf, qf[kk], a, 0, 0, 0);
        }
        S[n] = a;
      }
      if (kt == t) {
#pragma unroll
        for (int n = 0; n < 4; n++)
#pragma unroll
          for (int r = 0; r < 4; r++) {
            int key = kt * 64 + n * 16 + quad * 4 + r;
            if (key > qrow) S[n][r] = -1e9f;          // exp2 -> 0
          }
      }
#pragma unroll
      for (int n = 0; n < 4; n++) {
        float p0 = __builtin_amdgcn_exp2f(S[n][0]);
        float p1 = __builtin_amdgcn_exp2f(S[n][1]);
        float p2 = __builtin_amdgcn_exp2f(S[n][2]);
        float p3 = __builtin_amdgcn_exp2f(S[n][3]);
        l_acc += (p0 + p1) + (p2 + p3);
        short4 pk;
        pk.x = (short)f2bf_t(p0); pk.y = (short)f2bf_t(p1);
        pk.z = (short)f2bf_t(p2); pk.w = (short)f2bf_t(p3);
        *(short4*)(Pw + c * 72 + n * 16 + quad * 4) = pk;
      }
      bf16x8 pf[2];
#pragma unroll
      for (int kk2 = 0; kk2 < 2; kk2++)
        pf[kk2] = *(const bf16x8*)(Pw + c * 72 + kk2 * 32 + quad * 8);
#pragma unroll
      for (int md = 0; md < 8; md++)
#pragma unroll
        for (int kk2 = 0; kk2 < 2; kk2++) {
          bf16x8 vf = *(const bf16x8*)(Vs + kk2 * 4096 + (md * 16 + c) * 32 + swq);
          Oa[md] = __builtin_amdgcn_mfma_f32_16x16x32_bf16(vf, pf[kk2], Oa[md], 0, 0, 0);
        }
    }
    // strip epilogue: reduce l across quads, normalize, transpose, store
    float l_row = l_acc;
    l_row += __shfl_xor(l_row, 16);
    l_row += __shfl_xor(l_row, 32);
    __syncthreads();    // Ks/Vs now reusable as bounce space
    const float invl = 1.f / l_row;
#pragma unroll
    for (int md = 0; md < 8; md++) {
      short4 ok;
      ok.x = (short)f2bf(Oa[md][0] * invl); ok.y = (short)f2bf(Oa[md][1] * invl);
      ok.z = (short)f2bf(Oa[md][2] * invl); ok.w = (short)f2bf(Oa[md][3] * invl);
      *(short4*)(Bw + c * 136 + md * 16 + quad * 4) = ok;
    }
    const int orow = q0 + wave * 16 + lr;
#pragma unroll
    for (int tt = 0; tt < 4; tt++) {
      bf16x8 ov = *(const bf16x8*)(Bw + lr * 136 + lp * 32 + tt * 8);
      *(bf16x8*)(ob + ((size_t)(b * Q_ + orow) * HQ_ + h) * D_ + lp * 32 + tt * 8) = ov;
    }
  }
}

// ---------------- launcher ----------------
extern "C" void kernel_launch(void* const* d_in, const int* in_sizes, int n_in,
                              void* d_out, int out_size, void* d_ws, size_t ws_size,
                              hipStream_t stream) {
  const int*   positions = (const int*)  d_in[0];
  const float* hidden    = (const float*)d_in[1];
  const float* wqkv      = (const float*)d_in[4];
  const float* wo        = (const float*)d_in[5];
  const float* qnw       = (const float*)d_in[6];
  const float* knw       = (const float*)d_in[7];
  char* ws = (char*)d_ws;
  u16*   hid_bf  = (u16*)(ws);                     // 16,777,216
  u16*   wqkv_bf = (u16*)(ws + 16777216);          // 12,582,912
  u16*   wo_bf   = (u16*)(ws + 29360128);          //  8,388,608
  u16*   q_bf    = (u16*)(ws + 37748736);          // 16,777,216
  u16*   k_bf    = (u16*)(ws + 54525952);          //  4,194,304
  u16*   vt_bf   = (u16*)(ws + 58720256);          //  4,194,304
  float* rope    = (float*)(ws + 62914560);        //  2,097,152
  u16*   attn_bf = hid_bf;                         // alias: dead after gemm_qkv

  cvt_all<<<19456, 256, 0, stream>>>(hidden, wqkv, wo, positions,
                                     hid_bf, wqkv_bf, wo_bf, rope);
  gemm_qkv<<<dim3(32, 24), 256, 0, stream>>>(hid_bf, wqkv_bf, rope, qnw, knw,
                                             q_bf, k_bf, vt_bf);
  attn_fwd<<<dim3(16, 16, 2), 256, 0, stream>>>(q_bf, k_bf, vt_bf, attn_bf);
  gemm_bt<<<dim3(32, 16), 256, 0, stream>>>(attn_bf, wo_bf, (float*)d_out, 4096, 2048, 2048);
}